// Round 3
// baseline (199.352 us; speedup 1.0000x reference)
//
#include <hip/hip_runtime.h>
#include <math.h>

#define H 4096
#define W 4096
#define NC 512            // cells per dim (H/8)
#define NB 510            // blocks per dim (NC - 3 + 1)
#define ORI 9
#define NCELLS (NC * NC)  // 262144

// ---- glibc flt-32 atanf/atan2f replication (fdlibm; pre-2.40 glibc) ----
// atanhi/atanlo are the float-source constants (NOT casts of the doubles).
__device__ __constant__ float c_atanhi[4] = {
    4.6364760399e-01f,  /* atan(0.5)hi 0x3eed6338 */
    7.8539812565e-01f,  /* atan(1.0)hi 0x3f490fda */
    9.8279368877e-01f,  /* atan(1.5)hi 0x3f7b985e */
    1.5707962513e+00f,  /* atan(inf)hi 0x3fc90fda */
};
__device__ __constant__ float c_atanlo[4] = {
    5.0121582440e-09f,  /* atan(0.5)lo 0x31ac3769 */
    3.7748947079e-08f,  /* atan(1.0)lo 0x33222168 */
    3.4473217170e-08f,  /* atan(1.5)lo 0x33140fb4 */
    7.5497894159e-08f,  /* atan(inf)lo 0x33a22168 */
};

__device__ float fdlibm_atanf(float x) {
#pragma clang fp contract(off)
    const float one = 1.0f;
    // (float) casts of fdlibm's double aT[] — how glibc's flt-32 file was made.
    const float aT0  = (float) 3.33333333333329318027e-01;
    const float aT1  = (float)-1.99999999998764832476e-01;
    const float aT2  = (float) 1.42857142725034663711e-01;
    const float aT3  = (float)-1.11111104054623557880e-01;
    const float aT4  = (float) 9.09088713343650656196e-02;
    const float aT5  = (float)-7.69187620504482999495e-02;
    const float aT6  = (float) 6.66107313738753120669e-02;
    const float aT7  = (float)-5.83357013379057348645e-02;
    const float aT8  = (float) 4.97687799461593236017e-02;
    const float aT9  = (float)-3.65315727442169155270e-02;
    const float aT10 = (float) 1.62858201153657823623e-02;
    int hx = __float_as_int(x);
    int ix = hx & 0x7fffffff;
    int id;
    if (ix >= 0x4c800000) {            /* |x| >= 2^26 */
        if (ix > 0x7f800000) return x + x;  /* NaN */
        float r = c_atanhi[3] + c_atanlo[3];
        return (hx > 0) ? r : -r;
    }
    if (ix < 0x3ee00000) {             /* |x| < 0.4375 */
        if (ix < 0x31000000) return x; /* |x| < 2^-29 */
        id = -1;
    } else {
        x = fabsf(x);
        if (ix < 0x3f980000) {         /* |x| < 1.1875 */
            if (ix < 0x3f300000) { id = 0; x = (2.0f * x - one) / (2.0f + x); }
            else                 { id = 1; x = (x - one) / (x + one); }
        } else {
            if (ix < 0x401c0000) { id = 2; x = (x - 1.5f) / (one + 1.5f * x); }
            else                 { id = 3; x = -1.0f / x; }
        }
    }
    float z = x * x;
    float w = z * z;
    float s1 = z * (aT0 + w * (aT2 + w * (aT4 + w * (aT6 + w * (aT8 + w * aT10)))));
    float s2 = w * (aT1 + w * (aT3 + w * (aT5 + w * (aT7 + w * aT9))));
    if (id < 0) return x - x * (s1 + s2);
    z = c_atanhi[id] - ((x * (s1 + s2) - c_atanlo[id]) - x);
    return (hx < 0) ? -z : z;
}

__device__ float fdlibm_atan2f(float y, float x) {
#pragma clang fp contract(off)
    const float tiny   = 1.0e-30f;
    const float pi     = 3.1415927410e+00f;  /* 0x40490FDB */
    const float pi_lo  = -8.7422776573e-08f; /* 0xB3BBBD2E */
    const float pi_o_2 = 1.5707963705e+00f;  /* 0x3FC90FDB */
    int hx = __float_as_int(x), ix = hx & 0x7fffffff;
    int hy = __float_as_int(y), iy = hy & 0x7fffffff;
    if (ix > 0x7f800000 || iy > 0x7f800000) return x + y;  /* NaN */
    if (hx == 0x3f800000) return fdlibm_atanf(y);          /* x == 1.0 */
    int m = ((hy >> 31) & 1) | ((hx >> 30) & 2);
    if (iy == 0) {                      /* y = 0 */
        switch (m) {
            case 0: case 1: return y;
            case 2: return pi + tiny;
            default: return -pi - tiny;
        }
    }
    if (ix == 0) return (hy < 0) ? -pi_o_2 - tiny : pi_o_2 + tiny;  /* x = 0 */
    if (ix == 0x7f800000) {             /* x = inf (unreachable here) */
        if (iy == 0x7f800000) {
            switch (m) {
                case 0: return pi_o_2 * 0.5f + tiny;
                case 1: return -(pi_o_2 * 0.5f) - tiny;
                case 2: return 1.5f * pi_o_2 + tiny;
                default: return -(1.5f * pi_o_2) - tiny;
            }
        } else {
            switch (m) {
                case 0: return 0.0f;
                case 1: return -0.0f;
                case 2: return pi + tiny;
                default: return -pi - tiny;
            }
        }
    }
    if (iy == 0x7f800000) return (hy < 0) ? -pi_o_2 - tiny : pi_o_2 + tiny;
    int k = (iy - ix) >> 23;            /* |y/x| ~ 2^k */
    float z;
    if (k > 26) { z = pi_o_2 + 0.5f * pi_lo; m &= 1; }   /* |y/x| > 2^26 */
    else if (k < -26 && hx < 0) z = 0.0f;
    else z = fdlibm_atanf(fabsf(y / x));
    switch (m) {
        case 0: return z;
        case 1: return -z;
        case 2: return pi - (z - pi_lo);
        default: return (z - pi_lo) - pi;
    }
}
// ------------------------------------------------------------------------

// Correctly-rounded f32 sqrt of input pixel — bit-exact with np.sqrt(float32).
__device__ __forceinline__ float simg(const float* __restrict__ x, int r, int c) {
    return sqrtf(x[r * W + c]);
}

// Kernel A: per-cell 9-bin histogram of gradient magnitudes.
// 256 threads = 4 waves; each wave owns one 8x8 cell.
__global__ __launch_bounds__(256) void hog_hist(const float* __restrict__ x,
                                                float* __restrict__ hist) {
#pragma clang fp contract(off)
    int wave = threadIdx.x >> 6;
    int lane = threadIdx.x & 63;
    int cell = blockIdx.x * 4 + wave;
    int cr = cell >> 9;          // cell / 512
    int cc = cell & 511;
    int pr = (cr << 3) + (lane >> 3);
    int pc = (cc << 3) + (lane & 7);

    // float32-faithful numpy pipeline.
    float gy = 0.0f, gx = 0.0f;
    if (pr >= 1 && pr <= H - 2)
        gy = simg(x, pr + 1, pc) - simg(x, pr - 1, pc);   // exact f32 subtract
    if (pc >= 1 && pc <= W - 2)
        gx = simg(x, pr, pc + 1) - simg(x, pr, pc - 1);

    float ang = fdlibm_atan2f(gy, gx);                    // glibc atan2f replica
    const float RAD2DEG = (float)(180.0 / 3.14159265358979323846264338328); // 0x42652EE1
    float deg = ang * RAD2DEG;                            // numpy rad2deg f32
    float m = fmodf(deg, 180.0f);                         // exact
    if (m < 0.0f) m += 180.0f;                            // numpy mod semantics
    int bin = (int)(m / 20.0f);
    if (bin < 9 && m >= (float)((bin + 1) * 20)) bin++;   // division-rounding guard
    else if (bin > 0 && m < (float)(bin * 20)) bin--;
    // m == 180.0f -> bin 9 -> contributes to no bin (matches ori < 180).

    // magnitude: value-level only; ~correctly-rounded hypotf.
    double gyd = (double)gy, gxd = (double)gx;
    float mag = (float)sqrt(gyd * gyd + gxd * gxd);

    float s[ORI];
#pragma unroll
    for (int b = 0; b < ORI; ++b) s[b] = (bin == b) ? mag : 0.0f;
#pragma unroll
    for (int off = 32; off > 0; off >>= 1) {
#pragma unroll
        for (int b = 0; b < ORI; ++b) s[b] += __shfl_xor(s[b], off, 64);
    }
    if (lane < ORI) hist[cell * ORI + lane] = s[lane] * (1.0f / 64.0f);
}

// Kernel B: inverse block norm per (i,j): 1/sqrt(sum over 3x3x9 hist^2 + EPS^2)
__global__ __launch_bounds__(256) void hog_invd(const float* __restrict__ hist,
                                                float* __restrict__ invd) {
    int t = blockIdx.x * 256 + threadIdx.x;
    if (t >= NB * NB) return;
    int i = t / NB;
    int j = t - i * NB;
    float ssq = 0.0f;
#pragma unroll
    for (int bi = 0; bi < 3; ++bi) {
#pragma unroll
        for (int bj = 0; bj < 3; ++bj) {
            const float* h = &hist[((i + bi) * NC + (j + bj)) * ORI];
#pragma unroll
            for (int o = 0; o < ORI; ++o) ssq += h[o] * h[o];
        }
    }
    invd[t] = 1.0f / sqrtf(ssq + 1e-10f);
}

// Kernel C: fully coalesced normalized output write.
__global__ __launch_bounds__(256) void hog_norm(const float* __restrict__ hist,
                                                const float* __restrict__ invd,
                                                float* __restrict__ out, int n) {
    int k = blockIdx.x * 256 + threadIdx.x;
    if (k >= n) return;
    int r = k / 9;
    int o = k - r * 9;
    int bj = r % 3; r /= 3;
    int bi = r % 3; r /= 3;
    int j = r % NB;
    int i = r / NB;
    out[k] = hist[((i + bi) * NC + (j + bj)) * ORI + o] * invd[i * NB + j];
}

extern "C" void kernel_launch(void* const* d_in, const int* in_sizes, int n_in,
                              void* d_out, int out_size, void* d_ws, size_t ws_size,
                              hipStream_t stream) {
    const float* x = (const float*)d_in[0];
    float* out = (float*)d_out;
    // ws layout: hist (512*512*9 f32 = 9.44 MB) | invd (510*510 f32 = 1.04 MB)
    float* hist = (float*)d_ws;
    float* invd = hist + NCELLS * ORI;

    hog_hist<<<NCELLS / 4, 256, 0, stream>>>(x, hist);
    hog_invd<<<(NB * NB + 255) / 256, 256, 0, stream>>>(hist, invd);
    hog_norm<<<(out_size + 255) / 256, 256, 0, stream>>>(hist, invd, out, out_size);
}

// Round 4
// 191.773 us; speedup vs baseline: 1.0395x; 1.0395x over previous
//
#include <hip/hip_runtime.h>
#include <math.h>

#define H 4096
#define W 4096
#define NC 512            // cells per dim (H/8)
#define NB 510            // blocks per dim (NC - 3 + 1)
#define ORI 9
#define NCELLS (NC * NC)  // 262144

// ---- glibc flt-32 atanf/atan2f replication (fdlibm; pre-2.40 glibc) ----
// Used only on the rare near-boundary fallback path; must stay bit-exact.
__device__ __constant__ float c_atanhi[4] = {
    4.6364760399e-01f, 7.8539812565e-01f, 9.8279368877e-01f, 1.5707962513e+00f,
};
__device__ __constant__ float c_atanlo[4] = {
    5.0121582440e-09f, 3.7748947079e-08f, 3.4473217170e-08f, 7.5497894159e-08f,
};

__device__ float fdlibm_atanf(float x) {
#pragma clang fp contract(off)
    const float one = 1.0f;
    const float aT0  = (float) 3.33333333333329318027e-01;
    const float aT1  = (float)-1.99999999998764832476e-01;
    const float aT2  = (float) 1.42857142725034663711e-01;
    const float aT3  = (float)-1.11111104054623557880e-01;
    const float aT4  = (float) 9.09088713343650656196e-02;
    const float aT5  = (float)-7.69187620504482999495e-02;
    const float aT6  = (float) 6.66107313738753120669e-02;
    const float aT7  = (float)-5.83357013379057348645e-02;
    const float aT8  = (float) 4.97687799461593236017e-02;
    const float aT9  = (float)-3.65315727442169155270e-02;
    const float aT10 = (float) 1.62858201153657823623e-02;
    int hx = __float_as_int(x);
    int ix = hx & 0x7fffffff;
    int id;
    if (ix >= 0x4c800000) {
        if (ix > 0x7f800000) return x + x;
        float r = c_atanhi[3] + c_atanlo[3];
        return (hx > 0) ? r : -r;
    }
    if (ix < 0x3ee00000) {
        if (ix < 0x31000000) return x;
        id = -1;
    } else {
        x = fabsf(x);
        if (ix < 0x3f980000) {
            if (ix < 0x3f300000) { id = 0; x = (2.0f * x - one) / (2.0f + x); }
            else                 { id = 1; x = (x - one) / (x + one); }
        } else {
            if (ix < 0x401c0000) { id = 2; x = (x - 1.5f) / (one + 1.5f * x); }
            else                 { id = 3; x = -1.0f / x; }
        }
    }
    float z = x * x;
    float w = z * z;
    float s1 = z * (aT0 + w * (aT2 + w * (aT4 + w * (aT6 + w * (aT8 + w * aT10)))));
    float s2 = w * (aT1 + w * (aT3 + w * (aT5 + w * (aT7 + w * aT9))));
    if (id < 0) return x - x * (s1 + s2);
    z = c_atanhi[id] - ((x * (s1 + s2) - c_atanlo[id]) - x);
    return (hx < 0) ? -z : z;
}

__device__ float fdlibm_atan2f(float y, float x) {
#pragma clang fp contract(off)
    const float tiny   = 1.0e-30f;
    const float pi     = 3.1415927410e+00f;
    const float pi_lo  = -8.7422776573e-08f;
    const float pi_o_2 = 1.5707963705e+00f;
    int hx = __float_as_int(x), ix = hx & 0x7fffffff;
    int hy = __float_as_int(y), iy = hy & 0x7fffffff;
    if (ix > 0x7f800000 || iy > 0x7f800000) return x + y;
    if (hx == 0x3f800000) return fdlibm_atanf(y);
    int m = ((hy >> 31) & 1) | ((hx >> 30) & 2);
    if (iy == 0) {
        switch (m) {
            case 0: case 1: return y;
            case 2: return pi + tiny;
            default: return -pi - tiny;
        }
    }
    if (ix == 0) return (hy < 0) ? -pi_o_2 - tiny : pi_o_2 + tiny;
    if (ix == 0x7f800000) {
        if (iy == 0x7f800000) {
            switch (m) {
                case 0: return pi_o_2 * 0.5f + tiny;
                case 1: return -(pi_o_2 * 0.5f) - tiny;
                case 2: return 1.5f * pi_o_2 + tiny;
                default: return -(1.5f * pi_o_2) - tiny;
            }
        } else {
            switch (m) {
                case 0: return 0.0f;
                case 1: return -0.0f;
                case 2: return pi + tiny;
                default: return -pi - tiny;
            }
        }
    }
    if (iy == 0x7f800000) return (hy < 0) ? -pi_o_2 - tiny : pi_o_2 + tiny;
    int k = (iy - ix) >> 23;
    float z;
    if (k > 26) { z = pi_o_2 + 0.5f * pi_lo; m &= 1; }
    else if (k < -26 && hx < 0) z = 0.0f;
    else z = fdlibm_atanf(fabsf(y / x));
    switch (m) {
        case 0: return z;
        case 1: return -z;
        case 2: return pi - (z - pi_lo);
        default: return (z - pi_lo) - pi;
    }
}

// Exact-replica binning (slow path). Returns 0..8, or 9 == excluded (m==180 quirk).
__device__ __noinline__ int slow_bin(float gy, float gx) {
#pragma clang fp contract(off)
    float ang = fdlibm_atan2f(gy, gx);
    const float RAD2DEG = (float)(180.0 / 3.14159265358979323846264338328);
    float deg = ang * RAD2DEG;
    float m = fmodf(deg, 180.0f);
    if (m < 0.0f) m += 180.0f;
    int bin = (int)(m / 20.0f);
    if (bin < 9 && m >= (float)((bin + 1) * 20)) bin++;
    else if (bin > 0 && m < (float)(bin * 20)) bin--;
    return bin;
}
// ------------------------------------------------------------------------

__device__ __forceinline__ float simg(const float* __restrict__ x, int r, int c) {
    return sqrtf(x[r * W + c]);   // IEEE-exact: must match np.sqrt bit-for-bit
}

// Kernel A: per-cell 9-bin histogram. 4 waves/block; wave = one 8x8 cell.
// Fast branchless sign-test binning + rare bit-exact fdlibm fallback.
__global__ __launch_bounds__(256) void hog_hist(const float* __restrict__ x,
                                                float* __restrict__ hist) {
    int wave = threadIdx.x >> 6;
    int lane = threadIdx.x & 63;
    int cell = blockIdx.x * 4 + wave;
    int cr = cell >> 9;
    int cc = cell & 511;
    int pr = (cr << 3) + (lane >> 3);
    int pc = (cc << 3) + (lane & 7);

    float gy = 0.0f, gx = 0.0f;
    if (pr >= 1 && pr <= H - 2)
        gy = simg(x, pr + 1, pc) - simg(x, pr - 1, pc);   // exact f32
    if (pc >= 1 && pc <= W - 2)
        gx = simg(x, pr, pc + 1) - simg(x, pr, pc - 1);

    // --- fast path: bin via 8 half-plane sign tests (boundaries 20..160 deg) ---
    const float C1 = (float) 0.93969262078590838405, S1 = (float) 0.34202014332566873304;
    const float C2 = (float) 0.76604444311897803520, S2 = (float) 0.64278760968653932632;
    const float C3 = 0.5f,                           S3 = (float) 0.86602540378443864676;
    const float C4 = (float) 0.17364817766693034885, S4 = (float) 0.98480775301220805937;
    float cr1 = fmaf(gy, C1, -gx * S1);
    float cr2 = fmaf(gy, C2, -gx * S2);
    float cr3 = fmaf(gy, C3, -gx * S3);
    float cr4 = fmaf(gy, C4, -gx * S4);
    float cr5 = fmaf(gy, -C4, -gx * S4);
    float cr6 = fmaf(gy, -C3, -gx * S3);
    float cr7 = fmaf(gy, -C2, -gx * S2);
    float cr8 = fmaf(gy, -C1, -gx * S1);
    int cnt = (cr1 >= 0.0f) + (cr2 >= 0.0f) + (cr3 >= 0.0f) + (cr4 >= 0.0f)
            + (cr5 >= 0.0f) + (cr6 >= 0.0f) + (cr7 >= 0.0f) + (cr8 >= 0.0f);
    int bin = (gy < 0.0f) ? 8 - cnt : cnt;

    // near-boundary / near-horizontal guard -> bit-exact fallback
    float ay = fabsf(gy), ax = fabsf(gx);
    float r = ax + ay;
    float cm = fminf(fminf(fminf(fabsf(cr1), fabsf(cr2)), fminf(fabsf(cr3), fabsf(cr4))),
                     fminf(fminf(fabsf(cr5), fabsf(cr6)), fminf(fabsf(cr7), fabsf(cr8))));
    const float EPSA = 1e-5f;
    if (fminf(cm, ay) < EPSA * r) bin = slow_bin(gy, gx);  // whole-wave skip when none

    // magnitude: value-level only (never affects binning)
    float mag = sqrtf(fmaf(gy, gy, gx * gx));

    float s[ORI];
#pragma unroll
    for (int b = 0; b < ORI; ++b) s[b] = (bin == b) ? mag : 0.0f;
#pragma unroll
    for (int off = 32; off > 0; off >>= 1) {
#pragma unroll
        for (int b = 0; b < ORI; ++b) s[b] += __shfl_xor(s[b], off, 64);
    }
    if (lane < ORI) hist[cell * ORI + lane] = s[lane] * (1.0f / 64.0f);
}

// Kernel B: inverse block norm per (i,j)
__global__ __launch_bounds__(256) void hog_invd(const float* __restrict__ hist,
                                                float* __restrict__ invd) {
    int t = blockIdx.x * 256 + threadIdx.x;
    if (t >= NB * NB) return;
    int i = t / NB;
    int j = t - i * NB;
    float ssq = 0.0f;
#pragma unroll
    for (int bi = 0; bi < 3; ++bi) {
#pragma unroll
        for (int bj = 0; bj < 3; ++bj) {
            const float* h = &hist[((i + bi) * NC + (j + bj)) * ORI];
#pragma unroll
            for (int o = 0; o < ORI; ++o) ssq += h[o] * h[o];
        }
    }
    invd[t] = 1.0f / sqrtf(ssq + 1e-10f);
}

// Kernel C: fully coalesced normalized output write.
__global__ __launch_bounds__(256) void hog_norm(const float* __restrict__ hist,
                                                const float* __restrict__ invd,
                                                float* __restrict__ out, int n) {
    int k = blockIdx.x * 256 + threadIdx.x;
    if (k >= n) return;
    int r = k / 9;
    int o = k - r * 9;
    int bj = r % 3; r /= 3;
    int bi = r % 3; r /= 3;
    int j = r % NB;
    int i = r / NB;
    out[k] = hist[((i + bi) * NC + (j + bj)) * ORI + o] * invd[i * NB + j];
}

extern "C" void kernel_launch(void* const* d_in, const int* in_sizes, int n_in,
                              void* d_out, int out_size, void* d_ws, size_t ws_size,
                              hipStream_t stream) {
    const float* x = (const float*)d_in[0];
    float* out = (float*)d_out;
    float* hist = (float*)d_ws;                 // 512*512*9 f32 = 9.44 MB
    float* invd = hist + NCELLS * ORI;          // 510*510 f32 = 1.04 MB

    hog_hist<<<NCELLS / 4, 256, 0, stream>>>(x, hist);
    hog_invd<<<(NB * NB + 255) / 256, 256, 0, stream>>>(hist, invd);
    hog_norm<<<(out_size + 255) / 256, 256, 0, stream>>>(hist, invd, out, out_size);
}

// Round 5
// 164.214 us; speedup vs baseline: 1.2140x; 1.1678x over previous
//
#include <hip/hip_runtime.h>
#include <math.h>

#define H 4096
#define W 4096
#define NC 512            // cells per dim (H/8)
#define NB 510            // blocks per dim (NC - 3 + 1)
#define ORI 9
#define NCELLS (NC * NC)  // 262144

// ---- glibc flt-32 atanf/atan2f replication (fdlibm; pre-2.40 glibc) ----
// Used only on the rare near-boundary fallback path; must stay bit-exact.
__device__ __constant__ float c_atanhi[4] = {
    4.6364760399e-01f, 7.8539812565e-01f, 9.8279368877e-01f, 1.5707962513e+00f,
};
__device__ __constant__ float c_atanlo[4] = {
    5.0121582440e-09f, 3.7748947079e-08f, 3.4473217170e-08f, 7.5497894159e-08f,
};

__device__ float fdlibm_atanf(float x) {
#pragma clang fp contract(off)
    const float one = 1.0f;
    const float aT0  = (float) 3.33333333333329318027e-01;
    const float aT1  = (float)-1.99999999998764832476e-01;
    const float aT2  = (float) 1.42857142725034663711e-01;
    const float aT3  = (float)-1.11111104054623557880e-01;
    const float aT4  = (float) 9.09088713343650656196e-02;
    const float aT5  = (float)-7.69187620504482999495e-02;
    const float aT6  = (float) 6.66107313738753120669e-02;
    const float aT7  = (float)-5.83357013379057348645e-02;
    const float aT8  = (float) 4.97687799461593236017e-02;
    const float aT9  = (float)-3.65315727442169155270e-02;
    const float aT10 = (float) 1.62858201153657823623e-02;
    int hx = __float_as_int(x);
    int ix = hx & 0x7fffffff;
    int id;
    if (ix >= 0x4c800000) {
        if (ix > 0x7f800000) return x + x;
        float r = c_atanhi[3] + c_atanlo[3];
        return (hx > 0) ? r : -r;
    }
    if (ix < 0x3ee00000) {
        if (ix < 0x31000000) return x;
        id = -1;
    } else {
        x = fabsf(x);
        if (ix < 0x3f980000) {
            if (ix < 0x3f300000) { id = 0; x = (2.0f * x - one) / (2.0f + x); }
            else                 { id = 1; x = (x - one) / (x + one); }
        } else {
            if (ix < 0x401c0000) { id = 2; x = (x - 1.5f) / (one + 1.5f * x); }
            else                 { id = 3; x = -1.0f / x; }
        }
    }
    float z = x * x;
    float w = z * z;
    float s1 = z * (aT0 + w * (aT2 + w * (aT4 + w * (aT6 + w * (aT8 + w * aT10)))));
    float s2 = w * (aT1 + w * (aT3 + w * (aT5 + w * (aT7 + w * aT9))));
    if (id < 0) return x - x * (s1 + s2);
    z = c_atanhi[id] - ((x * (s1 + s2) - c_atanlo[id]) - x);
    return (hx < 0) ? -z : z;
}

__device__ float fdlibm_atan2f(float y, float x) {
#pragma clang fp contract(off)
    const float tiny   = 1.0e-30f;
    const float pi     = 3.1415927410e+00f;
    const float pi_lo  = -8.7422776573e-08f;
    const float pi_o_2 = 1.5707963705e+00f;
    int hx = __float_as_int(x), ix = hx & 0x7fffffff;
    int hy = __float_as_int(y), iy = hy & 0x7fffffff;
    if (ix > 0x7f800000 || iy > 0x7f800000) return x + y;
    if (hx == 0x3f800000) return fdlibm_atanf(y);
    int m = ((hy >> 31) & 1) | ((hx >> 30) & 2);
    if (iy == 0) {
        switch (m) {
            case 0: case 1: return y;
            case 2: return pi + tiny;
            default: return -pi - tiny;
        }
    }
    if (ix == 0) return (hy < 0) ? -pi_o_2 - tiny : pi_o_2 + tiny;
    if (ix == 0x7f800000) {
        if (iy == 0x7f800000) {
            switch (m) {
                case 0: return pi_o_2 * 0.5f + tiny;
                case 1: return -(pi_o_2 * 0.5f) - tiny;
                case 2: return 1.5f * pi_o_2 + tiny;
                default: return -(1.5f * pi_o_2) - tiny;
            }
        } else {
            switch (m) {
                case 0: return 0.0f;
                case 1: return -0.0f;
                case 2: return pi + tiny;
                default: return -pi - tiny;
            }
        }
    }
    if (iy == 0x7f800000) return (hy < 0) ? -pi_o_2 - tiny : pi_o_2 + tiny;
    int k = (iy - ix) >> 23;
    float z;
    if (k > 26) { z = pi_o_2 + 0.5f * pi_lo; m &= 1; }
    else if (k < -26 && hx < 0) z = 0.0f;
    else z = fdlibm_atanf(fabsf(y / x));
    switch (m) {
        case 0: return z;
        case 1: return -z;
        case 2: return pi - (z - pi_lo);
        default: return (z - pi_lo) - pi;
    }
}

// Exact-replica binning (slow path). Returns 0..8, or 9 == excluded (m==180 quirk).
__device__ __noinline__ int slow_bin(float gy, float gx) {
#pragma clang fp contract(off)
    float ang = fdlibm_atan2f(gy, gx);
    const float RAD2DEG = (float)(180.0 / 3.14159265358979323846264338328);
    float deg = ang * RAD2DEG;
    float m = fmodf(deg, 180.0f);
    if (m < 0.0f) m += 180.0f;
    int bin = (int)(m / 20.0f);
    if (bin < 9 && m >= (float)((bin + 1) * 20)) bin++;
    else if (bin > 0 && m < (float)(bin * 20)) bin--;
    return bin;
}
// ------------------------------------------------------------------------

__device__ __forceinline__ float simg(const float* __restrict__ x, int r, int c) {
    return sqrtf(x[r * W + c]);   // IEEE-exact: must match np.sqrt bit-for-bit
}

// Kernel A: per-cell 9-bin histogram. 4 waves/block; wave = one 8x8 cell.
// Branchless sign-test binning + rare bit-exact fdlibm fallback.
// Reduction via LDS atomic adds (1 ds_add_f32/pixel) instead of the
// 54-shuffle butterfly that dominated round 4.
__global__ __launch_bounds__(256) void hog_hist(const float* __restrict__ x,
                                                float* __restrict__ hist) {
    __shared__ float lh[4 * ORI];
    int t = threadIdx.x;
    if (t < 4 * ORI) lh[t] = 0.0f;
    __syncthreads();

    int wave = t >> 6;
    int lane = t & 63;
    int cell = blockIdx.x * 4 + wave;
    int cr = cell >> 9;
    int cc = cell & 511;
    int pr = (cr << 3) + (lane >> 3);
    int pc = (cc << 3) + (lane & 7);

    float gy = 0.0f, gx = 0.0f;
    if (pr >= 1 && pr <= H - 2)
        gy = simg(x, pr + 1, pc) - simg(x, pr - 1, pc);   // exact f32
    if (pc >= 1 && pc <= W - 2)
        gx = simg(x, pr, pc + 1) - simg(x, pr, pc - 1);

    // --- fast path: bin via 8 half-plane sign tests (boundaries 20..160 deg) ---
    const float C1 = (float) 0.93969262078590838405, S1 = (float) 0.34202014332566873304;
    const float C2 = (float) 0.76604444311897803520, S2 = (float) 0.64278760968653932632;
    const float C3 = 0.5f,                           S3 = (float) 0.86602540378443864676;
    const float C4 = (float) 0.17364817766693034885, S4 = (float) 0.98480775301220805937;
    float cr1 = fmaf(gy, C1, -gx * S1);
    float cr2 = fmaf(gy, C2, -gx * S2);
    float cr3 = fmaf(gy, C3, -gx * S3);
    float cr4 = fmaf(gy, C4, -gx * S4);
    float cr5 = fmaf(gy, -C4, -gx * S4);
    float cr6 = fmaf(gy, -C3, -gx * S3);
    float cr7 = fmaf(gy, -C2, -gx * S2);
    float cr8 = fmaf(gy, -C1, -gx * S1);
    int cnt = (cr1 >= 0.0f) + (cr2 >= 0.0f) + (cr3 >= 0.0f) + (cr4 >= 0.0f)
            + (cr5 >= 0.0f) + (cr6 >= 0.0f) + (cr7 >= 0.0f) + (cr8 >= 0.0f);
    int bin = (gy < 0.0f) ? 8 - cnt : cnt;

    // near-boundary / near-horizontal guard -> bit-exact fallback
    float ay = fabsf(gy), ax = fabsf(gx);
    float r = ax + ay;
    float cm = fminf(fminf(fminf(fabsf(cr1), fabsf(cr2)), fminf(fabsf(cr3), fabsf(cr4))),
                     fminf(fminf(fabsf(cr5), fabsf(cr6)), fminf(fabsf(cr7), fabsf(cr8))));
    const float EPSA = 1e-5f;
    if (fminf(cm, ay) < EPSA * r) bin = slow_bin(gy, gx);  // whole-wave skip when none

    // magnitude: value-level only (never affects binning)
    float mag = sqrtf(fmaf(gy, gy, gx * gx));

    // one LDS atomic per pixel; bin==9 (m==180 quirk) excluded
    if (bin < ORI) atomicAdd(&lh[wave * ORI + bin], mag);
    __syncthreads();

    // coalesced 144B store of the block's 4 cells
    if (t < 4 * ORI) hist[blockIdx.x * 4 * ORI + t] = lh[t] * (1.0f / 64.0f);
}

// Kernel B: inverse block norm per (i,j)
__global__ __launch_bounds__(256) void hog_invd(const float* __restrict__ hist,
                                                float* __restrict__ invd) {
    int t = blockIdx.x * 256 + threadIdx.x;
    if (t >= NB * NB) return;
    int i = t / NB;
    int j = t - i * NB;
    float ssq = 0.0f;
#pragma unroll
    for (int bi = 0; bi < 3; ++bi) {
#pragma unroll
        for (int bj = 0; bj < 3; ++bj) {
            const float* h = &hist[((i + bi) * NC + (j + bj)) * ORI];
#pragma unroll
            for (int o = 0; o < ORI; ++o) ssq += h[o] * h[o];
        }
    }
    invd[t] = 1.0f / sqrtf(ssq + 1e-10f);
}

// Kernel C: fully coalesced normalized output write.
__global__ __launch_bounds__(256) void hog_norm(const float* __restrict__ hist,
                                                const float* __restrict__ invd,
                                                float* __restrict__ out, int n) {
    int k = blockIdx.x * 256 + threadIdx.x;
    if (k >= n) return;
    int r = k / 9;
    int o = k - r * 9;
    int bj = r % 3; r /= 3;
    int bi = r % 3; r /= 3;
    int j = r % NB;
    int i = r / NB;
    out[k] = hist[((i + bi) * NC + (j + bj)) * ORI + o] * invd[i * NB + j];
}

extern "C" void kernel_launch(void* const* d_in, const int* in_sizes, int n_in,
                              void* d_out, int out_size, void* d_ws, size_t ws_size,
                              hipStream_t stream) {
    const float* x = (const float*)d_in[0];
    float* out = (float*)d_out;
    float* hist = (float*)d_ws;                 // 512*512*9 f32 = 9.44 MB
    float* invd = hist + NCELLS * ORI;          // 510*510 f32 = 1.04 MB

    hog_hist<<<NCELLS / 4, 256, 0, stream>>>(x, hist);
    hog_invd<<<(NB * NB + 255) / 256, 256, 0, stream>>>(hist, invd);
    hog_norm<<<(out_size + 255) / 256, 256, 0, stream>>>(hist, invd, out, out_size);
}

// Round 6
// 152.671 us; speedup vs baseline: 1.3058x; 1.0756x over previous
//
#include <hip/hip_runtime.h>
#include <math.h>

#define H 4096
#define W 4096
#define NC 512            // cells per dim (H/8)
#define NB 510            // blocks per dim (NC - 3 + 1)
#define ORI 9
#define NCELLS (NC * NC)  // 262144

// ---- glibc flt-32 atanf/atan2f replication (fdlibm; pre-2.40 glibc) ----
// Used only on the rare near-boundary fallback path; must stay bit-exact.
__device__ __constant__ float c_atanhi[4] = {
    4.6364760399e-01f, 7.8539812565e-01f, 9.8279368877e-01f, 1.5707962513e+00f,
};
__device__ __constant__ float c_atanlo[4] = {
    5.0121582440e-09f, 3.7748947079e-08f, 3.4473217170e-08f, 7.5497894159e-08f,
};

__device__ float fdlibm_atanf(float x) {
#pragma clang fp contract(off)
    const float one = 1.0f;
    const float aT0  = (float) 3.33333333333329318027e-01;
    const float aT1  = (float)-1.99999999998764832476e-01;
    const float aT2  = (float) 1.42857142725034663711e-01;
    const float aT3  = (float)-1.11111104054623557880e-01;
    const float aT4  = (float) 9.09088713343650656196e-02;
    const float aT5  = (float)-7.69187620504482999495e-02;
    const float aT6  = (float) 6.66107313738753120669e-02;
    const float aT7  = (float)-5.83357013379057348645e-02;
    const float aT8  = (float) 4.97687799461593236017e-02;
    const float aT9  = (float)-3.65315727442169155270e-02;
    const float aT10 = (float) 1.62858201153657823623e-02;
    int hx = __float_as_int(x);
    int ix = hx & 0x7fffffff;
    int id;
    if (ix >= 0x4c800000) {
        if (ix > 0x7f800000) return x + x;
        float r = c_atanhi[3] + c_atanlo[3];
        return (hx > 0) ? r : -r;
    }
    if (ix < 0x3ee00000) {
        if (ix < 0x31000000) return x;
        id = -1;
    } else {
        x = fabsf(x);
        if (ix < 0x3f980000) {
            if (ix < 0x3f300000) { id = 0; x = (2.0f * x - one) / (2.0f + x); }
            else                 { id = 1; x = (x - one) / (x + one); }
        } else {
            if (ix < 0x401c0000) { id = 2; x = (x - 1.5f) / (one + 1.5f * x); }
            else                 { id = 3; x = -1.0f / x; }
        }
    }
    float z = x * x;
    float w = z * z;
    float s1 = z * (aT0 + w * (aT2 + w * (aT4 + w * (aT6 + w * (aT8 + w * aT10)))));
    float s2 = w * (aT1 + w * (aT3 + w * (aT5 + w * (aT7 + w * aT9))));
    if (id < 0) return x - x * (s1 + s2);
    z = c_atanhi[id] - ((x * (s1 + s2) - c_atanlo[id]) - x);
    return (hx < 0) ? -z : z;
}

__device__ float fdlibm_atan2f(float y, float x) {
#pragma clang fp contract(off)
    const float tiny   = 1.0e-30f;
    const float pi     = 3.1415927410e+00f;
    const float pi_lo  = -8.7422776573e-08f;
    const float pi_o_2 = 1.5707963705e+00f;
    int hx = __float_as_int(x), ix = hx & 0x7fffffff;
    int hy = __float_as_int(y), iy = hy & 0x7fffffff;
    if (ix > 0x7f800000 || iy > 0x7f800000) return x + y;
    if (hx == 0x3f800000) return fdlibm_atanf(y);
    int m = ((hy >> 31) & 1) | ((hx >> 30) & 2);
    if (iy == 0) {
        switch (m) {
            case 0: case 1: return y;
            case 2: return pi + tiny;
            default: return -pi - tiny;
        }
    }
    if (ix == 0) return (hy < 0) ? -pi_o_2 - tiny : pi_o_2 + tiny;
    if (ix == 0x7f800000) {
        if (iy == 0x7f800000) {
            switch (m) {
                case 0: return pi_o_2 * 0.5f + tiny;
                case 1: return -(pi_o_2 * 0.5f) - tiny;
                case 2: return 1.5f * pi_o_2 + tiny;
                default: return -(1.5f * pi_o_2) - tiny;
            }
        } else {
            switch (m) {
                case 0: return 0.0f;
                case 1: return -0.0f;
                case 2: return pi + tiny;
                default: return -pi - tiny;
            }
        }
    }
    if (iy == 0x7f800000) return (hy < 0) ? -pi_o_2 - tiny : pi_o_2 + tiny;
    int k = (iy - ix) >> 23;
    float z;
    if (k > 26) { z = pi_o_2 + 0.5f * pi_lo; m &= 1; }
    else if (k < -26 && hx < 0) z = 0.0f;
    else z = fdlibm_atanf(fabsf(y / x));
    switch (m) {
        case 0: return z;
        case 1: return -z;
        case 2: return pi - (z - pi_lo);
        default: return (z - pi_lo) - pi;
    }
}

// Exact-replica binning (slow path). Returns 0..8, or 9 == excluded (m==180 quirk).
__device__ __noinline__ int slow_bin(float gy, float gx) {
#pragma clang fp contract(off)
    float ang = fdlibm_atan2f(gy, gx);
    const float RAD2DEG = (float)(180.0 / 3.14159265358979323846264338328);
    float deg = ang * RAD2DEG;
    float m = fmodf(deg, 180.0f);
    if (m < 0.0f) m += 180.0f;
    int bin = (int)(m / 20.0f);
    if (bin < 9 && m >= (float)((bin + 1) * 20)) bin++;
    else if (bin > 0 && m < (float)(bin * 20)) bin--;
    return bin;
}

// Fast branchless bin via 8 half-plane sign tests; falls back to the
// bit-exact replica near boundaries / near-horizontal gradients.
__device__ __forceinline__ int bin_pixel(float gy, float gx) {
    const float C1 = (float) 0.93969262078590838405, S1 = (float) 0.34202014332566873304;
    const float C2 = (float) 0.76604444311897803520, S2 = (float) 0.64278760968653932632;
    const float C3 = 0.5f,                           S3 = (float) 0.86602540378443864676;
    const float C4 = (float) 0.17364817766693034885, S4 = (float) 0.98480775301220805937;
    float cr1 = fmaf(gy, C1, -gx * S1);
    float cr2 = fmaf(gy, C2, -gx * S2);
    float cr3 = fmaf(gy, C3, -gx * S3);
    float cr4 = fmaf(gy, C4, -gx * S4);
    float cr5 = fmaf(gy, -C4, -gx * S4);
    float cr6 = fmaf(gy, -C3, -gx * S3);
    float cr7 = fmaf(gy, -C2, -gx * S2);
    float cr8 = fmaf(gy, -C1, -gx * S1);
    int cnt = (cr1 >= 0.0f) + (cr2 >= 0.0f) + (cr3 >= 0.0f) + (cr4 >= 0.0f)
            + (cr5 >= 0.0f) + (cr6 >= 0.0f) + (cr7 >= 0.0f) + (cr8 >= 0.0f);
    int bin = (gy < 0.0f) ? 8 - cnt : cnt;
    float ay = fabsf(gy), ax = fabsf(gx);
    float r = ax + ay;
    float cm = fminf(fminf(fminf(fabsf(cr1), fabsf(cr2)), fminf(fabsf(cr3), fabsf(cr4))),
                     fminf(fminf(fabsf(cr5), fabsf(cr6)), fminf(fabsf(cr7), fabsf(cr8))));
    const float EPSA = 1e-5f;
    if (fminf(cm, ay) < EPSA * r) bin = slow_bin(gy, gx);
    return bin;
}

// Kernel A: block = one 64x8 pixel strip (8 cells). sqrt(x) staged once in LDS
// (1.3 sqrt+load per pixel instead of 5+4), gradients from LDS, LDS-atomic
// histogram with <=8-way collisions across 8 cells.
__global__ __launch_bounds__(256) void hog_hist(const float* __restrict__ x,
                                                float* __restrict__ hist) {
    __shared__ float S[10 * 68];   // sqrt tile, origin (row0-1, col0-1), 66 cols used
    __shared__ float lh[8 * 12];   // 8 cells x 9 bins (padded to 12)
    int t = threadIdx.x;
    int strip = blockIdx.x & 63;
    int crow  = blockIdx.x >> 6;
    int row0 = crow << 3;
    int col0 = strip << 6;

    if (t < 96) lh[t] = 0.0f;
    for (int i = t; i < 660; i += 256) {          // 10 rows x 66 cols
        int tr = i / 66;
        int tc = i - tr * 66;
        int grow = row0 - 1 + tr;
        int gcol = col0 - 1 + tc;
        float v = 0.0f;
        if ((unsigned)grow < (unsigned)H && (unsigned)gcol < (unsigned)W)
            v = sqrtf(x[grow * W + gcol]);        // IEEE-exact, matches np.sqrt
        S[tr * 68 + tc] = v;
    }
    __syncthreads();

#pragma unroll
    for (int pp = 0; pp < 2; ++pp) {
        int p = t + pp * 256;                     // 512 px per block
        int prow = p >> 6;
        int pcol = p & 63;
        int gr = row0 + prow;
        int gc = col0 + pcol;
        float gy = 0.0f, gx = 0.0f;
        if (gr >= 1 && gr <= H - 2)
            gy = S[(prow + 2) * 68 + pcol + 1] - S[prow * 68 + pcol + 1];
        if (gc >= 1 && gc <= W - 2)
            gx = S[(prow + 1) * 68 + pcol + 2] - S[(prow + 1) * 68 + pcol];
        int bin = bin_pixel(gy, gx);
        float mag = sqrtf(fmaf(gy, gy, gx * gx)); // value-level only
        if (bin < ORI) atomicAdd(&lh[(pcol >> 3) * 12 + bin], mag);
    }
    __syncthreads();

    if (t < 72) {                                 // 8 cells x 9 bins, coalesced
        int cl = t / 9;
        int b  = t - cl * 9;
        hist[crow * (NC * ORI) + strip * 72 + t] = lh[cl * 12 + b] * (1.0f / 64.0f);
    }
}

// Fused B+C: one wave per (i,j) block position. Lane l covers output elements
// l and l+64 (l<17) of the 81-element block; 6-step shuffle reduce for the
// norm; 81 consecutive coalesced output floats per wave.
__global__ __launch_bounds__(256) void hog_out(const float* __restrict__ hist,
                                               float* __restrict__ out) {
    int w = threadIdx.x >> 6;
    int l = threadIdx.x & 63;
    int pidx = blockIdx.x * 4 + w;                // grid exact: NB*NB = 4*65025
    int i = pidx / NB;
    int j = pidx - i * NB;

    int bi1 = l / 27, r1 = l - bi1 * 27;
    int bj1 = r1 / 9, o1 = r1 - bj1 * 9;
    float hv0 = hist[((i + bi1) * NC + (j + bj1)) * ORI + o1];
    float hv1 = 0.0f;
    if (l < 17) {
        int e = l + 64;
        int bi2 = e / 27, r2 = e - bi2 * 27;
        int bj2 = r2 / 9, o2 = r2 - bj2 * 9;
        hv1 = hist[((i + bi2) * NC + (j + bj2)) * ORI + o2];
    }
    float ssq = fmaf(hv0, hv0, hv1 * hv1);
#pragma unroll
    for (int off = 32; off > 0; off >>= 1) ssq += __shfl_xor(ssq, off, 64);
    float inv = 1.0f / sqrtf(ssq + 1e-10f);       // EPS^2 = 1e-10

    int base = pidx * 81;
    out[base + l] = hv0 * inv;
    if (l < 17) out[base + 64 + l] = hv1 * inv;
}

extern "C" void kernel_launch(void* const* d_in, const int* in_sizes, int n_in,
                              void* d_out, int out_size, void* d_ws, size_t ws_size,
                              hipStream_t stream) {
    const float* x = (const float*)d_in[0];
    float* out = (float*)d_out;
    float* hist = (float*)d_ws;                   // 512*512*9 f32 = 9.44 MB

    hog_hist<<<(NC / 8) * NC / 8 * 8, 256, 0, stream>>>(x, hist);  // 512 rows * 64 strips
    hog_out<<<(NB * NB) / 4, 256, 0, stream>>>(hist, out);
}